// Round 13
// baseline (94.990 us; speedup 1.0000x reference)
//
#include <hip/hip_runtime.h>

typedef __bf16 bf16;
typedef __bf16 bf16x4 __attribute__((ext_vector_type(4)));
typedef __bf16 bf16x8 __attribute__((ext_vector_type(8)));
typedef float f32x4 __attribute__((ext_vector_type(4)));

#define DEV __device__ __forceinline__

typedef const __attribute__((address_space(1))) void gvoid_t;
typedef __attribute__((address_space(3))) void lvoid_t;

DEV void gload_lds16(const void* g, void* l) {
  __builtin_amdgcn_global_load_lds((gvoid_t*)g, (lvoid_t*)l, 16, 0, 0);
}

DEV f32x4 mfma16(bf16x8 a, bf16x8 b, f32x4 c) {
  return __builtin_amdgcn_mfma_f32_16x16x32_bf16(a, b, c, 0, 0, 0);
}

// scores in exp2 domain: Q pre-scaled by 0.125 * log2(e) in the GEMM epilogue.
#define QSCALE 0.18033688011112042f

// ---------------------------------------------------------------------------
// Kernel A: fused f32 -> bf16 conversion of hidden_states + Wq|Wk|Wv.
// ---------------------------------------------------------------------------
__global__ __launch_bounds__(256) void cvt_all(
    const float* __restrict__ hs, const float* __restrict__ Wq,
    const float* __restrict__ Wk, const float* __restrict__ Wv,
    bf16* __restrict__ Xb, bf16* __restrict__ Wb) {
  const int i = blockIdx.x * 256 + threadIdx.x;  // float4 index
  const float* src;
  bf16* dst;
  int off;
  if (i < 1048576) {
    src = hs; dst = Xb; off = i;
  } else {
    const int j = i - 1048576;
    const int sel = j >> 18;
    off = j & 262143;
    src = (sel == 0) ? Wq : (sel == 1) ? Wk : Wv;
    dst = Wb + (size_t)sel * 1048576;
  }
  float4 f = reinterpret_cast<const float4*>(src)[off];
  bf16x4 o;
  o[0] = (bf16)f.x; o[1] = (bf16)f.y; o[2] = (bf16)f.z; o[3] = (bf16)f.w;
  reinterpret_cast<bf16x4*>(dst)[off] = o;
}

// ---------------------------------------------------------------------------
// Kernel B: fused QKV projection GEMM (unchanged from R12).
// ---------------------------------------------------------------------------
__global__ __launch_bounds__(256) void gemm_qkv(
    const bf16* __restrict__ X, const bf16* __restrict__ W,
    const float* __restrict__ bq, const float* __restrict__ bk,
    const float* __restrict__ bv,
    bf16* __restrict__ Q, bf16* __restrict__ Kb, bf16* __restrict__ Vt) {
  __shared__ bf16 As[128 * 64];
  __shared__ bf16 Bs[128 * 64];
  const int t = threadIdx.x;
  const int lane = t & 63, w = t >> 6;
  const int wr = w >> 1, wc = w & 1;
  const int bid = blockIdx.x;
  const int swz = (bid & 7) * 96 + (bid >> 3);  // XCD swizzle, 768%8==0
  const int m0 = (swz / 24) * 128;
  const int n0 = (swz % 24) * 128;
  const int cl = lane & 15, g8 = (lane >> 4) * 8;

  f32x4 acc[4][4];
  for (int mi = 0; mi < 4; ++mi)
    for (int ni = 0; ni < 4; ++ni)
      for (int r = 0; r < 4; ++r) acc[mi][ni][r] = 0.0f;

  for (int k0 = 0; k0 < 1024; k0 += 64) {
#pragma unroll
    for (int i = 0; i < 4; ++i) {
      int c = i * 256 + t;
      int row = c >> 3, col8 = (c & 7) * 8;
      gload_lds16(X + (size_t)(m0 + row) * 1024 + k0 + col8, As + c * 8);
      gload_lds16(W + (size_t)(n0 + row) * 1024 + k0 + col8, Bs + c * 8);
    }
    __syncthreads();
#pragma unroll
    for (int kk = 0; kk < 64; kk += 32) {
      bf16x8 a[4], b[4];
#pragma unroll
      for (int mi = 0; mi < 4; ++mi)
        a[mi] = *(const bf16x8*)&As[(wr * 64 + mi * 16 + cl) * 64 + kk + g8];
#pragma unroll
      for (int ni = 0; ni < 4; ++ni)
        b[ni] = *(const bf16x8*)&Bs[(wc * 64 + ni * 16 + cl) * 64 + kk + g8];
      __builtin_amdgcn_s_setprio(1);
#pragma unroll
      for (int mi = 0; mi < 4; ++mi)
#pragma unroll
        for (int ni = 0; ni < 4; ++ni)
          acc[mi][ni] = mfma16(a[mi], b[ni], acc[mi][ni]);
      __builtin_amdgcn_s_setprio(0);
    }
    __syncthreads();
  }

  const int rq = (lane >> 4) * 4;
#pragma unroll
  for (int mi = 0; mi < 4; ++mi) {
#pragma unroll
    for (int ni = 0; ni < 4; ++ni) {
      const int n = n0 + wc * 64 + ni * 16 + cl;
      const int mbase = m0 + wr * 64 + mi * 16 + rq;
      const int b = mbase >> 11, s0 = mbase & 2047;
      if (n < 1024) {
        const float bias = bq[n];
        const int h = n >> 6, hd = n & 63;
#pragma unroll
        for (int r = 0; r < 4; ++r)
          Q[(((size_t)(b * 16 + h)) * 2048 + s0 + r) * 64 + hd] =
              (bf16)((acc[mi][ni][r] + bias) * QSCALE);
      } else if (n < 2048) {
        const int n2 = n - 1024;
        const float bias = bk[n2];
        const int h = n2 >> 6, hd = n2 & 63;
#pragma unroll
        for (int r = 0; r < 4; ++r)
          Kb[(((size_t)(b * 16 + h)) * 2048 + s0 + r) * 64 + hd] =
              (bf16)(acc[mi][ni][r] + bias);
      } else {
        const int n2 = n - 2048;
        const float bias = bv[n2];
        const int h = n2 >> 6, hd = n2 & 63;
        bf16x4 pk;
#pragma unroll
        for (int r = 0; r < 4; ++r) pk[r] = (bf16)(acc[mi][ni][r] + bias);
        *(bf16x4*)&Vt[(((size_t)(b * 16 + h)) * 64 + hd) * 2048 + s0] = pk;
      }
    }
  }
}

// ---------------------------------------------------------------------------
// Kernel C: causal flash attention v13 = v12 + PV-lag software pipeline.
// Block = 8 waves (512 thr); waves 0-3 own q-tile qhi=31-p, waves 4-7 own
// qlo=p. Fixed-max softmax (QK acc init -12, p = exp2(s)). Per iteration kt:
// stage tile kt+1 (K 2-slot, V 3-slot ring), then hot path {QK(kt),
// PV(kt-1), exp(kt), Pwrite(kt)} in ONE wave-uniform block so PV's MFMAs
// overlap exp's VALU/trans work. Ps double-buffered per wave. One barrier
// per iteration. Epilogue drains PV(qt) for hi waves.
// Race audit: K slot kt&1 written iter kt-1 / read iter kt (barrier between);
// V slot kt%3 written iter kt-1, read iter kt+1, rewritten iter kt+2 —
// every write/read pair separated by >=1 barrier; Ps is wave-local.
// ---------------------------------------------------------------------------
__global__ __launch_bounds__(512) void flash_attn(
    const bf16* __restrict__ Q, const bf16* __restrict__ K,
    const bf16* __restrict__ Vt, const int* __restrict__ amask,
    float* __restrict__ out) {
  __shared__ bf16 Ks[2][64 * 64];
  __shared__ bf16 Vs[3][64 * 64];
  __shared__ bf16 Ps[8][2][16 * 64];
  const int t = threadIdx.x, lane = t & 63, w = t >> 6;
  const int bh = blockIdx.x & 31;  // same bh -> same XCD (L2-resident KV)
  const int p = blockIdx.x >> 5;   // 0..15
  const int qt = (w < 4) ? (31 - p) : p;  // this wave's 64-row q tile
  const int b = bh >> 4, h = bh & 15;
  const int cl = lane & 15, g8 = (lane >> 4) * 8, rq = (lane >> 4) * 4;
  const int row0 = qt * 64 + (w & 3) * 16;
  const int ntiles = 32 - p;

  const bf16* Qp = Q + (size_t)bh * 2048 * 64;
  const bf16* Kp = K + (size_t)bh * 2048 * 64;
  const bf16* Vp = Vt + (size_t)bh * 64 * 2048;

  bf16x8 qf[2];
#pragma unroll
  for (int ks = 0; ks < 2; ++ks)
    qf[ks] = *(const bf16x8*)&Qp[(size_t)(row0 + cl) * 64 + ks * 32 + g8];

  // ones B-fragment: B[0][k]=1 -> col 0 of D = rowsum
  bf16x8 ones;
#pragma unroll
  for (int j = 0; j < 8; ++j) ones[j] = (cl == 0) ? (bf16)1.0f : (bf16)0.0f;

  f32x4 o[5];
#pragma unroll
  for (int nc = 0; nc < 5; ++nc)
#pragma unroll
    for (int r = 0; r < 4; ++r) o[nc][r] = 0.0f;

  // PV of tile j: Ps slot psl, V slot vsl
  auto PV = [&](int psl, int vsl) {
    __builtin_amdgcn_s_setprio(1);
#pragma unroll
    for (int ks = 0; ks < 2; ++ks) {
      const bf16x8 pa = *(const bf16x8*)&Ps[w][psl][cl * 64 +
                            ((ks * 32 + g8) ^ ((cl & 7) << 3))];
#pragma unroll
      for (int nc = 0; nc < 4; ++nc) {
        const int row = nc * 16 + cl;
        const bf16x8 vf = *(const bf16x8*)&Vs[vsl][row * 64 +
                              ((ks * 32 + g8) ^ ((row & 7) << 3))];
        o[nc] = mfma16(pa, vf, o[nc]);
      }
      o[4] = mfma16(pa, ones, o[4]);
    }
    __builtin_amdgcn_s_setprio(0);
  };

  // prologue: stage tile 0 into K slot 0 / V slot 0.
  {
    const int row = t >> 3, sl8 = ((t & 7) ^ (row & 7)) * 8;
    gload_lds16(Kp + (size_t)row * 64 + sl8, &Ks[0][t * 8]);
    gload_lds16(Vp + (size_t)row * 2048 + sl8, &Vs[0][t * 8]);
  }
  __syncthreads();

  int v1 = 1;  // V ring slot of tile kt+1
  for (int kt = 0; kt < ntiles; ++kt) {
    const int kv0 = kt * 64;
    if (kt + 1 < ntiles) {  // prefetch tile kt+1
      const int row = t >> 3, sl8 = ((t & 7) ^ (row & 7)) * 8;
      gload_lds16(Kp + (size_t)(kv0 + 64 + row) * 64 + sl8,
                  &Ks[(kt + 1) & 1][t * 8]);
      gload_lds16(Vp + (size_t)row * 2048 + kv0 + 64 + sl8, &Vs[v1][t * 8]);
    }
    const int vm1 = (v1 + 1) % 3;  // slot of tile kt-1 (= (kt-1)%3)
    const bool doQK = (kt <= qt);
    const bool doPV = (kt >= 1) & (kt <= qt + 1);
    if (doQK & doPV) {
      // ---- hot path: QK(kt) + PV(kt-1) + exp(kt) in one block
      const unsigned long long padb =
          __ballot(amask[b * 2048 + kv0 + lane] != 0);
      f32x4 s4[4];
#pragma unroll
      for (int nj = 0; nj < 4; ++nj)
#pragma unroll
        for (int r = 0; r < 4; ++r) s4[nj][r] = -12.0f;
      __builtin_amdgcn_s_setprio(1);
#pragma unroll
      for (int ks = 0; ks < 2; ++ks) {
#pragma unroll
        for (int nj = 0; nj < 4; ++nj) {
          const int row = nj * 16 + cl;
          const bf16x8 kf = *(const bf16x8*)&Ks[kt & 1][row * 64 +
                                ((ks * 32 + g8) ^ ((row & 7) << 3))];
          s4[nj] = mfma16(qf[ks], kf, s4[nj]);
        }
      }
      __builtin_amdgcn_s_setprio(0);
      PV((kt & 1) ^ 1, vm1);  // overlaps with exp below on separate pipes
      const bool needm = (kt == qt) || (padb != 0ull);
#pragma unroll
      for (int nj = 0; nj < 4; ++nj)
#pragma unroll
        for (int r = 0; r < 4; ++r) {
          float x = s4[nj][r];
          if (needm) {
            const int col = kv0 + nj * 16 + cl;
            const int rowq = row0 + rq + r;
            const bool bad = (col > rowq) || ((padb >> (nj * 16 + cl)) & 1ull);
            x = bad ? -1e30f : x;
          }
          const float pv = __builtin_amdgcn_exp2f(x);
          const int rr = rq + r;
          Ps[w][kt & 1][rr * 64 + ((nj * 16 + cl) ^ ((rr & 7) << 3))] =
              (bf16)pv;
        }
    } else if (doQK) {
      // ---- kt == 0: QK + exp only
      const unsigned long long padb =
          __ballot(amask[b * 2048 + kv0 + lane] != 0);
      f32x4 s4[4];
#pragma unroll
      for (int nj = 0; nj < 4; ++nj)
#pragma unroll
        for (int r = 0; r < 4; ++r) s4[nj][r] = -12.0f;
      __builtin_amdgcn_s_setprio(1);
#pragma unroll
      for (int ks = 0; ks < 2; ++ks) {
#pragma unroll
        for (int nj = 0; nj < 4; ++nj) {
          const int row = nj * 16 + cl;
          const bf16x8 kf = *(const bf16x8*)&Ks[kt & 1][row * 64 +
                                ((ks * 32 + g8) ^ ((row & 7) << 3))];
          s4[nj] = mfma16(qf[ks], kf, s4[nj]);
        }
      }
      __builtin_amdgcn_s_setprio(0);
      const bool needm = (kt == qt) || (padb != 0ull);
#pragma unroll
      for (int nj = 0; nj < 4; ++nj)
#pragma unroll
        for (int r = 0; r < 4; ++r) {
          float x = s4[nj][r];
          if (needm) {
            const int col = kv0 + nj * 16 + cl;
            const int rowq = row0 + rq + r;
            const bool bad = (col > rowq) || ((padb >> (nj * 16 + cl)) & 1ull);
            x = bad ? -1e30f : x;
          }
          const float pv = __builtin_amdgcn_exp2f(x);
          const int rr = rq + r;
          Ps[w][kt & 1][rr * 64 + ((nj * 16 + cl) ^ ((rr & 7) << 3))] =
              (bf16)pv;
        }
    } else if (doPV) {
      // ---- lo waves, kt == qt+1: drain last PV
      PV((kt & 1) ^ 1, vm1);
    }
    __syncthreads();
    v1 = (v1 + 1) % 3;
  }

  // ---- epilogue: hi waves drain PV(qt) (qt == ntiles-1 -> never ran in-loop)
  if (w < 4) {
    // slot of tile qt = (ntiles-1): v1 currently = (ntiles+1)%3 -> qt%3 = v1+1
    PV(qt & 1, (v1 + 1) % 3);
  }

  // ---- normalize by rowsum (col 0 of o[4]) and store
#pragma unroll
  for (int r = 0; r < 4; ++r) {
    const float l = __shfl(o[4][r], lane & 48, 64);
    const float inv = 1.0f / l;
    const int rowg = row0 + rq + r;
    float* op = &out[((size_t)b * 2048 + rowg) * 1024 + h * 64];
#pragma unroll
    for (int nc = 0; nc < 4; ++nc) op[nc * 16 + cl] = o[nc][r] * inv;
  }
}

// ---------------------------------------------------------------------------
extern "C" void kernel_launch(void* const* d_in, const int* in_sizes, int n_in,
                              void* d_out, int out_size, void* d_ws,
                              size_t ws_size, hipStream_t stream) {
  const float* hs = (const float*)d_in[0];
  const int* amask = (const int*)d_in[1];
  const float* Wq = (const float*)d_in[2];
  const float* bq = (const float*)d_in[3];
  const float* Wk = (const float*)d_in[4];
  const float* bk = (const float*)d_in[5];
  const float* Wv = (const float*)d_in[6];
  const float* bv = (const float*)d_in[7];
  float* out = (float*)d_out;

  char* ws = (char*)d_ws;
  bf16* Xb = (bf16*)ws;                               // 8 MB: [4096][1024]
  bf16* Wb = (bf16*)(ws + 8ull * 1024 * 1024);        // 6 MB: [3072][1024]
  bf16* Qb = (bf16*)(ws + 14ull * 1024 * 1024);       // 8 MB: [32][2048][64]
  bf16* Kb = (bf16*)(ws + 22ull * 1024 * 1024);       // 8 MB: [32][2048][64]
  bf16* Vtb = (bf16*)(ws + 30ull * 1024 * 1024);      // 8 MB: [32][64][2048]

  cvt_all<<<7168, 256, 0, stream>>>(hs, Wq, Wk, Wv, Xb, Wb);
  gemm_qkv<<<768, 256, 0, stream>>>(Xb, Wb, bq, bk, bv, Qb, Kb, Vtb);
  flash_attn<<<512, 512, 0, stream>>>(Qb, Kb, Vtb, amask, out);
}